// Round 2
// baseline (4111.686 us; speedup 1.0000x reference)
//
#include <hip/hip_runtime.h>

// ColumnSelfAttention (ESM-style) — fp32 baseline, conflict-tuned.
// Shapes: x (R=128, C=384, B=1, E=768); H=12 heads, D=64.
// out = [ output (R*C*E floats) | attn_probs (H*C*R*R floats) ]
// Workspace: q | k | v, each M*E floats (453 MB total).
// q is reused in-place for the attention context (each (c,h,i-half) slice is
// read only by the block that overwrites it).

#define R_ 128
#define C_ 384
#define E_ 768
#define H_ 12
#define D_ 64
#define M_ (R_ * C_)   // 49152

// ---------------------------------------------------------------------------
// GEMM: out[m,n] = (sum_k A[m,k] * W[n,k] + bias[n]) * scale
// A: (M x K) row-major; W: (N x K) row-major (torch Linear layout -> B^T GEMM).
// BM=BN=128, BK=16, 256 threads, split 8x8 micro-tile:
//   rows {ty*4+i, 64+ty*4+i}, cols {tx*4+j, 64+tx*4+j}  (conflict-free LDS reads)
// ---------------------------------------------------------------------------
__global__ __launch_bounds__(256) void gemm_bt(
    const float* __restrict__ A, const float* __restrict__ W,
    const float* __restrict__ bias, float* __restrict__ out,
    int M, int N, int K, float scale)
{
  __shared__ float As[16][128];   // k-major
  __shared__ float Bs[16][128];
  const int tid = threadIdx.x;
  const int tx = tid & 15, ty = tid >> 4;
  const int bm = blockIdx.x * 128, bn = blockIdx.y * 128;
  // staging: idx = tid + 256*it (it=0,1): row = idx>>2 (0..127), c4 = (idx&3)*4
  const int srow = tid >> 2;              // 0..63 (it=0); +64 for it=1
  const int sc4  = (tid & 3) << 2;
  const float* Ap0 = A + (size_t)(bm + srow) * K + sc4;
  const float* Ap1 = A + (size_t)(bm + 64 + srow) * K + sc4;
  const float* Wp0 = W + (size_t)(bn + srow) * K + sc4;
  const float* Wp1 = W + (size_t)(bn + 64 + srow) * K + sc4;

  float acc[8][8] = {};
  for (int k0 = 0; k0 < K; k0 += 16) {
    float4 a0 = *(const float4*)(Ap0 + k0);
    float4 a1 = *(const float4*)(Ap1 + k0);
    float4 w0 = *(const float4*)(Wp0 + k0);
    float4 w1 = *(const float4*)(Wp1 + k0);
    __syncthreads();                      // previous iter's LDS reads done
    As[sc4+0][srow]    = a0.x; As[sc4+1][srow]    = a0.y;
    As[sc4+2][srow]    = a0.z; As[sc4+3][srow]    = a0.w;
    As[sc4+0][64+srow] = a1.x; As[sc4+1][64+srow] = a1.y;
    As[sc4+2][64+srow] = a1.z; As[sc4+3][64+srow] = a1.w;
    Bs[sc4+0][srow]    = w0.x; Bs[sc4+1][srow]    = w0.y;
    Bs[sc4+2][srow]    = w0.z; Bs[sc4+3][srow]    = w0.w;
    Bs[sc4+0][64+srow] = w1.x; Bs[sc4+1][64+srow] = w1.y;
    Bs[sc4+2][64+srow] = w1.z; Bs[sc4+3][64+srow] = w1.w;
    __syncthreads();
    #pragma unroll
    for (int k = 0; k < 16; ++k) {
      float4 av0 = *(const float4*)&As[k][ty * 4];        // ty-broadcast, banks 0..15
      float4 av1 = *(const float4*)&As[k][64 + ty * 4];
      float4 bv0 = *(const float4*)&Bs[k][tx * 4];        // 16B lane stride: 2-way, free
      float4 bv1 = *(const float4*)&Bs[k][64 + tx * 4];
      float av[8] = {av0.x, av0.y, av0.z, av0.w, av1.x, av1.y, av1.z, av1.w};
      float bv[8] = {bv0.x, bv0.y, bv0.z, bv0.w, bv1.x, bv1.y, bv1.z, bv1.w};
      #pragma unroll
      for (int i = 0; i < 8; ++i)
        #pragma unroll
        for (int j = 0; j < 8; ++j)
          acc[i][j] = fmaf(av[i], bv[j], acc[i][j]);
    }
  }
  // epilogue: (acc + bias) * scale
  float bb[8];
  #pragma unroll
  for (int j = 0; j < 4; ++j) {
    bb[j]     = bias[bn + tx * 4 + j];
    bb[j + 4] = bias[bn + 64 + tx * 4 + j];
  }
  #pragma unroll
  for (int i = 0; i < 8; ++i) {
    int row = (i < 4) ? (bm + ty * 4 + i) : (bm + 64 + ty * 4 + (i - 4));
    float4 r0, r1;
    r0.x = (acc[i][0] + bb[0]) * scale; r0.y = (acc[i][1] + bb[1]) * scale;
    r0.z = (acc[i][2] + bb[2]) * scale; r0.w = (acc[i][3] + bb[3]) * scale;
    r1.x = (acc[i][4] + bb[4]) * scale; r1.y = (acc[i][5] + bb[5]) * scale;
    r1.z = (acc[i][6] + bb[6]) * scale; r1.w = (acc[i][7] + bb[7]) * scale;
    *(float4*)&out[(size_t)row * N + bn + tx * 4]      = r0;
    *(float4*)&out[(size_t)row * N + bn + 64 + tx * 4] = r1;
  }
}

// ---------------------------------------------------------------------------
// Attention: per (c, h, row-half) block.
// K tile stored with XOR d-granule swizzle: element (row,d) lives at
//   KsP[row*64 + (((d>>2) ^ (row>>3)) << 2) + (d&3)]
// so the score loop's 16 tx lanes (rows tx*8+j, (row>>3)==tx) spread across
// banks instead of a 16-way single-bank pile-up.
// LDS: Qs 16KB + KsP 32KB + Vs 32KB = 80KB -> 2 blocks/CU.
// 256 threads as 16(tx) x 16(ty): 4 score-rows x 8 score-cols per thread.
// ---------------------------------------------------------------------------
__global__ __launch_bounds__(256) void attn_kernel(
    const float* __restrict__ q, const float* __restrict__ kmat,
    const float* __restrict__ vmat, const unsigned char* __restrict__ mask,
    float* __restrict__ probs, float* __restrict__ ctx)
{
  __shared__ float Qs[64 * 64];     // this half's 64 q-rows (linear)
  __shared__ float KsP[128 * 64];   // K (swizzled) during scores; P (64x128) after
  __shared__ float Vs[128 * 64];    // linear
  const int c = blockIdx.x, h = blockIdx.y;
  const int i0 = blockIdx.z * 64;
  const int tid = threadIdx.x;
  const int tx = tid & 15, ty = tid >> 4;
  const size_t rstride = (size_t)C_ * E_;
  const size_t base = (size_t)c * E_ + (size_t)h * D_;

  // ---- stage Q (64x64 linear), K (128x64 swizzled), V (128x64 linear)
  #pragma unroll
  for (int it = 0; it < 4; ++it) {
    int idx = tid + 256 * it;                      // 1024 float4s
    int row = idx >> 4, c4 = (idx & 15) << 2;
    *(float4*)&Qs[row * 64 + c4] =
        *(const float4*)&q[base + (size_t)(i0 + row) * rstride + c4];
  }
  #pragma unroll
  for (int it = 0; it < 8; ++it) {
    int idx = tid + 256 * it;                      // 2048 float4s
    int row = idx >> 4, c4 = (idx & 15) << 2;
    int sw = (((c4 >> 2) ^ (row >> 3)) << 2);
    *(float4*)&KsP[row * 64 + sw] =
        *(const float4*)&kmat[base + (size_t)row * rstride + c4];
    *(float4*)&Vs[row * 64 + c4] =
        *(const float4*)&vmat[base + (size_t)row * rstride + c4];
  }
  __syncthreads();

  // ---- scores: rows i0+ty*4..+3, cols tx*8..+7
  float s[4][8] = {};
  #pragma unroll
  for (int d4 = 0; d4 < 64; d4 += 4) {
    float4 qv[4], kv[8];
    #pragma unroll
    for (int r = 0; r < 4; ++r)
      qv[r] = *(const float4*)&Qs[(ty * 4 + r) * 64 + d4];
    #pragma unroll
    for (int j = 0; j < 8; ++j)     // row = tx*8+j, row>>3 == tx
      kv[j] = *(const float4*)&KsP[(tx * 8 + j) * 64 + ((((d4 >> 2) ^ tx) & 15) << 2)];
    #pragma unroll
    for (int r = 0; r < 4; ++r)
      #pragma unroll
      for (int j = 0; j < 8; ++j)
        s[r][j] += qv[r].x * kv[j].x + qv[r].y * kv[j].y +
                   qv[r].z * kv[j].z + qv[r].w * kv[j].w;
  }

  // ---- padding mask (B=1, R, C): masked j-row -> -10000
  #pragma unroll
  for (int j = 0; j < 8; ++j) {
    if (mask[(size_t)(tx * 8 + j) * C_ + c]) {
      #pragma unroll
      for (int r = 0; r < 4; ++r) s[r][j] = -10000.0f;
    }
  }

  // ---- softmax over j (cols split across 16 tx lanes)
  float inv[4];
  #pragma unroll
  for (int r = 0; r < 4; ++r) {
    float m = s[r][0];
    #pragma unroll
    for (int j = 1; j < 8; ++j) m = fmaxf(m, s[r][j]);
    #pragma unroll
    for (int d = 1; d < 16; d <<= 1) m = fmaxf(m, __shfl_xor(m, d));
    float sum = 0.f;
    #pragma unroll
    for (int j = 0; j < 8; ++j) { s[r][j] = __expf(s[r][j] - m); sum += s[r][j]; }
    #pragma unroll
    for (int d = 1; d < 16; d <<= 1) sum += __shfl_xor(sum, d);
    inv[r] = 1.0f / sum;
  }

  __syncthreads();   // all K reads done before KsP is reused for P

  // ---- write probs (d_out) and stage P into KsP as [64][128] (linear)
  #pragma unroll
  for (int r = 0; r < 4; ++r) {
    float p[8];
    #pragma unroll
    for (int j = 0; j < 8; ++j) p[j] = s[r][j] * inv[r];
    size_t po = ((size_t)(h * C_ + c) * R_ + i0 + ty * 4 + r) * R_ + tx * 8;
    *(float4*)&probs[po]     = make_float4(p[0], p[1], p[2], p[3]);
    *(float4*)&probs[po + 4] = make_float4(p[4], p[5], p[6], p[7]);
    *(float4*)&KsP[(ty * 4 + r) * 128 + tx * 8]     = make_float4(p[0], p[1], p[2], p[3]);
    *(float4*)&KsP[(ty * 4 + r) * 128 + tx * 8 + 4] = make_float4(p[4], p[5], p[6], p[7]);
  }
  __syncthreads();

  // ---- context: rows ty*4..+3, d-cols tx*4..+3, sum over 128 j
  float cacc[4][4] = {};
  #pragma unroll 4
  for (int j = 0; j < 128; ++j) {
    float4 vj = *(const float4*)&Vs[j * 64 + tx * 4];    // 2-way, free
    #pragma unroll
    for (int r = 0; r < 4; ++r) {
      float pr = KsP[(ty * 4 + r) * 128 + j];            // ty-broadcast, free
      cacc[r][0] = fmaf(pr, vj.x, cacc[r][0]);
      cacc[r][1] = fmaf(pr, vj.y, cacc[r][1]);
      cacc[r][2] = fmaf(pr, vj.z, cacc[r][2]);
      cacc[r][3] = fmaf(pr, vj.w, cacc[r][3]);
    }
  }
  #pragma unroll
  for (int r = 0; r < 4; ++r) {
    size_t co = base + (size_t)(i0 + ty * 4 + r) * rstride + tx * 4;
    *(float4*)&ctx[co] = make_float4(cacc[r][0], cacc[r][1], cacc[r][2], cacc[r][3]);
  }
}

// ---------------------------------------------------------------------------
extern "C" void kernel_launch(void* const* d_in, const int* in_sizes, int n_in,
                              void* d_out, int out_size, void* d_ws, size_t ws_size,
                              hipStream_t stream) {
  const float* x  = (const float*)d_in[0];
  // d_in[1] = distances (unused)
  const unsigned char* mask = (const unsigned char*)d_in[2];  // bool, (1,R,C)
  const float* wq = (const float*)d_in[3];
  const float* bq = (const float*)d_in[4];
  const float* wk = (const float*)d_in[5];
  const float* bk = (const float*)d_in[6];
  const float* wv = (const float*)d_in[7];
  const float* bv = (const float*)d_in[8];
  const float* wo = (const float*)d_in[9];
  const float* bo = (const float*)d_in[10];

  float* out   = (float*)d_out;                       // (R,C,B,E)
  float* probs = out + (size_t)M_ * E_;               // (H,C,B,R,R)
  float* q = (float*)d_ws;
  float* k = q + (size_t)M_ * E_;
  float* v = k + (size_t)M_ * E_;

  const float scaling = 0.125f;                       // D^-0.5, D=64
  dim3 gproj(M_ / 128, E_ / 128);                     // 384 x 6

  gemm_bt<<<gproj, 256, 0, stream>>>(x, wq, bq, q, M_, E_, E_, scaling);
  gemm_bt<<<gproj, 256, 0, stream>>>(x, wk, bk, k, M_, E_, E_, 1.0f);
  gemm_bt<<<gproj, 256, 0, stream>>>(x, wv, bv, v, M_, E_, E_, 1.0f);

  attn_kernel<<<dim3(C_, H_, 2), 256, 0, stream>>>(q, k, v, mask, probs, q);

  gemm_bt<<<gproj, 256, 0, stream>>>(q, wo, bo, out, M_, E_, E_, 1.0f);
}

// Round 4
// 2192.104 us; speedup vs baseline: 1.8757x; 1.8757x over previous
//
#include <hip/hip_runtime.h>

// ColumnSelfAttention — bf16-MFMA projections (3x-split, fp32-class accuracy).
// Shapes: x (R=128, C=384, B=1, E=768); H=12 heads, D=64.
// out = [ output (R*C*E f32) | attn_probs (H*C*R*R f32) ]
// ws: q|k|v f32 (453 MB, q reused as packed ctx hi/lo) + 8 weight splits
//     (9.4 MB) => 462.4 MB.  x_hi/x_lo live in d_out's probs region (dead
//     until attn writes probs, strictly after the QKV GEMMs).

#define R_ 128
#define C_ 384
#define E_ 768
#define H_ 12
#define D_ 64
#define M_ (R_ * C_)   // 49152

typedef __bf16 bf16x8 __attribute__((ext_vector_type(8)));
typedef float  f32x4  __attribute__((ext_vector_type(4)));

static __device__ __forceinline__ unsigned short f2bf(float f) {
  unsigned u = __float_as_uint(f);
  u += 0x7FFFu + ((u >> 16) & 1u);          // RNE
  return (unsigned short)(u >> 16);
}
static __device__ __forceinline__ float bf2f(unsigned short h) {
  return __uint_as_float(((unsigned)h) << 16);
}

// ---------------------------------------------------------------------------
// split: fp32 -> (hi, lo) bf16 pair, hi+lo ~= v to 2^-17 rel.
// ---------------------------------------------------------------------------
__global__ __launch_bounds__(256) void split_kernel(
    const float* __restrict__ in, unsigned short* __restrict__ hi,
    unsigned short* __restrict__ lo, int n4)
{
  int i = blockIdx.x * 256 + threadIdx.x;
  int stride = gridDim.x * 256;
  for (; i < n4; i += stride) {
    float4 v = ((const float4*)in)[i];
    ushort4 h, l;
    h.x = f2bf(v.x); l.x = f2bf(v.x - bf2f(h.x));
    h.y = f2bf(v.y); l.y = f2bf(v.y - bf2f(h.y));
    h.z = f2bf(v.z); l.z = f2bf(v.z - bf2f(h.z));
    h.w = f2bf(v.w); l.w = f2bf(v.w - bf2f(h.w));
    ((ushort4*)hi)[i] = h;
    ((ushort4*)lo)[i] = l;
  }
}

// ---------------------------------------------------------------------------
// MFMA GEMM: out[m,n] = (sum_k A[m,k]*W[n,k] + bias[n]) * scale
// A given as bf16 hi/lo (possibly interleaved: row stride lda ushorts, k-tile
// base k0*kscaleA + chunk; Al may be Ah+64 for the packed-ctx layout).
// W hi/lo separate arrays, row-major K-contiguous (ldb = K).
// 128x128 tile, BK=64, 4 waves (2x2 of 64x64), mfma_f32_16x16x32_bf16,
// 3 MFMAs per frag pair (hh, hl, lh). LDS 64KB. XOR-8 chunk swizzle with
// pre-swizzled global source feeding linear global_load_lds (16B/lane):
//   LDS[row][ch] = G[row][ch ^ (row&7)]; reader xors back -> <=2-way banks.
// ---------------------------------------------------------------------------
__global__ __launch_bounds__(256) void gemm_mfma_split(
    const unsigned short* __restrict__ Ah, const unsigned short* __restrict__ Al,
    int lda, int kscaleA,
    const unsigned short* __restrict__ Bh, const unsigned short* __restrict__ Bl,
    const float* __restrict__ bias, float* __restrict__ out,
    int M, int N, int K, float scale)
{
  __shared__ unsigned short smem[4 * 128 * 64];   // Ah | Al | Bh | Bl (16KB each)
  unsigned short* sAh = smem;
  unsigned short* sAl = smem + 8192;
  unsigned short* sBh = smem + 16384;
  unsigned short* sBl = smem + 24576;
  const int tid  = threadIdx.x;
  const int w    = tid >> 6;
  const int lane = tid & 63;
  const int bm = blockIdx.x * 128, bn = blockIdx.y * 128;
  const int wm = (w >> 1) * 64,    wn = (w & 1) * 64;
  // staging lane geometry: 8 rows x 8 chunks (16B each) per wave-call
  const int lrow = lane >> 3;                 // 0..7 == row&7 (r0 is 8-aligned)
  const int lch  = ((lane & 7) ^ lrow) << 3;  // pre-swizzled k-offset (ushorts)

  f32x4 acc[4][4];
  #pragma unroll
  for (int i = 0; i < 4; ++i)
    #pragma unroll
    for (int j = 0; j < 4; ++j) acc[i][j] = (f32x4){0.f, 0.f, 0.f, 0.f};

  for (int k0 = 0; k0 < K; k0 += 64) {
    __syncthreads();                          // prior LDS reads complete
    #pragma unroll
    for (int c = 0; c < 4; ++c) {
      const int r0 = c * 32 + w * 8;          // wave-uniform
      const size_t ga = (size_t)(bm + r0 + lrow) * lda + (size_t)k0 * kscaleA + lch;
      const size_t gb = (size_t)(bn + r0 + lrow) * K + k0 + lch;
      __builtin_amdgcn_global_load_lds(
          (const __attribute__((address_space(1))) void*)(Ah + ga),
          (__attribute__((address_space(3))) void*)(sAh + r0 * 64), 16, 0, 0);
      __builtin_amdgcn_global_load_lds(
          (const __attribute__((address_space(1))) void*)(Al + ga),
          (__attribute__((address_space(3))) void*)(sAl + r0 * 64), 16, 0, 0);
      __builtin_amdgcn_global_load_lds(
          (const __attribute__((address_space(1))) void*)(Bh + gb),
          (__attribute__((address_space(3))) void*)(sBh + r0 * 64), 16, 0, 0);
      __builtin_amdgcn_global_load_lds(
          (const __attribute__((address_space(1))) void*)(Bl + gb),
          (__attribute__((address_space(3))) void*)(sBl + r0 * 64), 16, 0, 0);
    }
    __syncthreads();                          // compiler drains vmcnt before barrier

    #pragma unroll
    for (int ks = 0; ks < 2; ++ks) {
      bf16x8 ah[4], al[4], bh[4], bl[4];
      #pragma unroll
      for (int i = 0; i < 4; ++i) {
        const int ra = wm + i * 16 + (lane & 15);
        const int ca = (ks * 4 + (lane >> 4)) ^ (ra & 7);
        const int oa = ra * 64 + ca * 8;
        ah[i] = *(const bf16x8*)&sAh[oa];
        al[i] = *(const bf16x8*)&sAl[oa];
        const int rb = wn + i * 16 + (lane & 15);
        const int cb = (ks * 4 + (lane >> 4)) ^ (rb & 7);
        const int ob = rb * 64 + cb * 8;
        bh[i] = *(const bf16x8*)&sBh[ob];
        bl[i] = *(const bf16x8*)&sBl[ob];
      }
      #pragma unroll
      for (int i = 0; i < 4; ++i)
        #pragma unroll
        for (int j = 0; j < 4; ++j) {
          acc[i][j] = __builtin_amdgcn_mfma_f32_16x16x32_bf16(ah[i], bh[j], acc[i][j], 0, 0, 0);
          acc[i][j] = __builtin_amdgcn_mfma_f32_16x16x32_bf16(ah[i], bl[j], acc[i][j], 0, 0, 0);
          acc[i][j] = __builtin_amdgcn_mfma_f32_16x16x32_bf16(al[i], bh[j], acc[i][j], 0, 0, 0);
        }
    }
  }

  // epilogue: C/D map col=lane&15, row=(lane>>4)*4+reg  [m89-verified]
  #pragma unroll
  for (int j = 0; j < 4; ++j) {
    const int col = bn + wn + j * 16 + (lane & 15);
    const float b = bias[col];
    #pragma unroll
    for (int i = 0; i < 4; ++i) {
      const int row0 = bm + wm + i * 16 + ((lane >> 4) << 2);
      #pragma unroll
      for (int r = 0; r < 4; ++r)
        out[(size_t)(row0 + r) * N + col] = (acc[i][j][r] + b) * scale;
    }
  }
}

// ---------------------------------------------------------------------------
// Attention: per (c, h, row-half) block — fp32 core unchanged from the passed
// R2 version. ctx emitted as PACKED bf16 hi/lo over the q buffer: within each
// (i,c,h) 256-byte head-span, hi occupies bytes [0,128), lo [128,256).
// Writes land byte-exactly inside the q slice this block read -> in-place safe.
// ---------------------------------------------------------------------------
__global__ __launch_bounds__(256) void attn_kernel(
    const float* __restrict__ q, const float* __restrict__ kmat,
    const float* __restrict__ vmat, const unsigned char* __restrict__ mask,
    float* __restrict__ probs, unsigned short* __restrict__ ctx)
{
  __shared__ float Qs[64 * 64];
  __shared__ float KsP[128 * 64];
  __shared__ float Vs[128 * 64];
  const int c = blockIdx.x, h = blockIdx.y;
  const int i0 = blockIdx.z * 64;
  const int tid = threadIdx.x;
  const int tx = tid & 15, ty = tid >> 4;
  const size_t rstride = (size_t)C_ * E_;
  const size_t base = (size_t)c * E_ + (size_t)h * D_;

  #pragma unroll
  for (int it = 0; it < 4; ++it) {
    int idx = tid + 256 * it;
    int row = idx >> 4, c4 = (idx & 15) << 2;
    *(float4*)&Qs[row * 64 + c4] =
        *(const float4*)&q[base + (size_t)(i0 + row) * rstride + c4];
  }
  #pragma unroll
  for (int it = 0; it < 8; ++it) {
    int idx = tid + 256 * it;
    int row = idx >> 4, c4 = (idx & 15) << 2;
    int sw = (((c4 >> 2) ^ (row >> 3)) << 2);
    *(float4*)&KsP[row * 64 + sw] =
        *(const float4*)&kmat[base + (size_t)row * rstride + c4];
    *(float4*)&Vs[row * 64 + c4] =
        *(const float4*)&vmat[base + (size_t)row * rstride + c4];
  }
  __syncthreads();

  float s[4][8] = {};
  #pragma unroll
  for (int d4 = 0; d4 < 64; d4 += 4) {
    float4 qv[4], kv[8];
    #pragma unroll
    for (int r = 0; r < 4; ++r)
      qv[r] = *(const float4*)&Qs[(ty * 4 + r) * 64 + d4];
    #pragma unroll
    for (int j = 0; j < 8; ++j)
      kv[j] = *(const float4*)&KsP[(tx * 8 + j) * 64 + ((((d4 >> 2) ^ tx) & 15) << 2)];
    #pragma unroll
    for (int r = 0; r < 4; ++r)
      #pragma unroll
      for (int j = 0; j < 8; ++j)
        s[r][j] += qv[r].x * kv[j].x + qv[r].y * kv[j].y +
                   qv[r].z * kv[j].z + qv[r].w * kv[j].w;
  }

  #pragma unroll
  for (int j = 0; j < 8; ++j) {
    if (mask[(size_t)(tx * 8 + j) * C_ + c]) {
      #pragma unroll
      for (int r = 0; r < 4; ++r) s[r][j] = -10000.0f;
    }
  }

  float inv[4];
  #pragma unroll
  for (int r = 0; r < 4; ++r) {
    float m = s[r][0];
    #pragma unroll
    for (int j = 1; j < 8; ++j) m = fmaxf(m, s[r][j]);
    #pragma unroll
    for (int d = 1; d < 16; d <<= 1) m = fmaxf(m, __shfl_xor(m, d));
    float sum = 0.f;
    #pragma unroll
    for (int j = 0; j < 8; ++j) { s[r][j] = __expf(s[r][j] - m); sum += s[r][j]; }
    #pragma unroll
    for (int d = 1; d < 16; d <<= 1) sum += __shfl_xor(sum, d);
    inv[r] = 1.0f / sum;
  }

  __syncthreads();

  #pragma unroll
  for (int r = 0; r < 4; ++r) {
    float p[8];
    #pragma unroll
    for (int j = 0; j < 8; ++j) p[j] = s[r][j] * inv[r];
    size_t po = ((size_t)(h * C_ + c) * R_ + i0 + ty * 4 + r) * R_ + tx * 8;
    *(float4*)&probs[po]     = make_float4(p[0], p[1], p[2], p[3]);
    *(float4*)&probs[po + 4] = make_float4(p[4], p[5], p[6], p[7]);
    *(float4*)&KsP[(ty * 4 + r) * 128 + tx * 8]     = make_float4(p[0], p[1], p[2], p[3]);
    *(float4*)&KsP[(ty * 4 + r) * 128 + tx * 8 + 4] = make_float4(p[4], p[5], p[6], p[7]);
  }
  __syncthreads();

  float cacc[4][4] = {};
  #pragma unroll 4
  for (int j = 0; j < 128; ++j) {
    float4 vj = *(const float4*)&Vs[j * 64 + tx * 4];
    #pragma unroll
    for (int r = 0; r < 4; ++r) {
      float pr = KsP[(ty * 4 + r) * 128 + j];
      cacc[r][0] = fmaf(pr, vj.x, cacc[r][0]);
      cacc[r][1] = fmaf(pr, vj.y, cacc[r][1]);
      cacc[r][2] = fmaf(pr, vj.z, cacc[r][2]);
      cacc[r][3] = fmaf(pr, vj.w, cacc[r][3]);
    }
  }
  // packed ctx: ushort offset (m)*1536 + h*128 + d  (hi), +64 (lo)
  #pragma unroll
  for (int r = 0; r < 4; ++r) {
    const size_t m = (size_t)(i0 + ty * 4 + r) * C_ + c;
    const size_t co = m * 1536 + (size_t)h * 128 + tx * 4;
    ushort4 h4, l4;
    h4.x = f2bf(cacc[r][0]); l4.x = f2bf(cacc[r][0] - bf2f(h4.x));
    h4.y = f2bf(cacc[r][1]); l4.y = f2bf(cacc[r][1] - bf2f(h4.y));
    h4.z = f2bf(cacc[r][2]); l4.z = f2bf(cacc[r][2] - bf2f(h4.z));
    h4.w = f2bf(cacc[r][3]); l4.w = f2bf(cacc[r][3] - bf2f(h4.w));
    *(ushort4*)&ctx[co]      = h4;
    *(ushort4*)&ctx[co + 64] = l4;
  }
}

// ---------------------------------------------------------------------------
extern "C" void kernel_launch(void* const* d_in, const int* in_sizes, int n_in,
                              void* d_out, int out_size, void* d_ws, size_t ws_size,
                              hipStream_t stream) {
  const float* x  = (const float*)d_in[0];
  const unsigned char* mask = (const unsigned char*)d_in[2];
  const float* wq = (const float*)d_in[3];
  const float* bq = (const float*)d_in[4];
  const float* wk = (const float*)d_in[5];
  const float* bk = (const float*)d_in[6];
  const float* wv = (const float*)d_in[7];
  const float* bv = (const float*)d_in[8];
  const float* wo = (const float*)d_in[9];
  const float* bo = (const float*)d_in[10];

  float* out   = (float*)d_out;
  float* probs = out + (size_t)M_ * E_;

  const size_t ME = (size_t)M_ * E_;       // 37,748,736
  const size_t EE = (size_t)E_ * E_;       // 589,824
  char* wsb = (char*)d_ws;
  float* q = (float*)wsb;                  // reused as packed ctx after attn
  float* k = q + ME;
  float* v = k + ME;
  unsigned short* wsp = (unsigned short*)(wsb + 3 * ME * 4);  // 8 x EE splits
  unsigned short* wq_hi = wsp + 0 * EE, *wq_lo = wsp + 1 * EE;
  unsigned short* wk_hi = wsp + 2 * EE, *wk_lo = wsp + 3 * EE;
  unsigned short* wv_hi = wsp + 4 * EE, *wv_lo = wsp + 5 * EE;
  unsigned short* wo_hi = wsp + 6 * EE, *wo_lo = wsp + 7 * EE;
  // x splits live in d_out's probs region (302 MB >= 151 MB), dead once attn
  // starts writing probs (strictly after the QKV GEMMs).
  unsigned short* x_hi = (unsigned short*)probs;
  unsigned short* x_lo = x_hi + ME;
  unsigned short* ctx  = (unsigned short*)q;   // packed hi/lo per head-span

  split_kernel<<<2048, 256, 0, stream>>>(x,  x_hi,  x_lo,  (int)(ME / 4));
  split_kernel<<<576, 256, 0, stream>>>(wq, wq_hi, wq_lo, (int)(EE / 4));
  split_kernel<<<576, 256, 0, stream>>>(wk, wk_hi, wk_lo, (int)(EE / 4));
  split_kernel<<<576, 256, 0, stream>>>(wv, wv_hi, wv_lo, (int)(EE / 4));
  split_kernel<<<576, 256, 0, stream>>>(wo, wo_hi, wo_lo, (int)(EE / 4));

  const float scaling = 0.125f;            // D^-0.5
  dim3 gproj(M_ / 128, E_ / 128);          // 384 x 6

  gemm_mfma_split<<<gproj, 256, 0, stream>>>(x_hi, x_lo, E_, 1, wq_hi, wq_lo, bq, q, M_, E_, E_, scaling);
  gemm_mfma_split<<<gproj, 256, 0, stream>>>(x_hi, x_lo, E_, 1, wk_hi, wk_lo, bk, k, M_, E_, E_, 1.0f);
  gemm_mfma_split<<<gproj, 256, 0, stream>>>(x_hi, x_lo, E_, 1, wv_hi, wv_lo, bv, v, M_, E_, E_, 1.0f);

  attn_kernel<<<dim3(C_, H_, 2), 256, 0, stream>>>(q, k, v, mask, probs, ctx);

  gemm_mfma_split<<<gproj, 256, 0, stream>>>(ctx, ctx + 64, 1536, 2, wo_hi, wo_lo, bo, out, M_, E_, E_, 1.0f);
}